// Round 12
// baseline (64.690 us; speedup 1.0000x reference)
//
#include <hip/hip_runtime.h>
#include <hip/hip_bf16.h>

// Problem dims (fixed by reference)
#define N_IN   1024     // K
#define N_P    1024     // N (= 32*32 lifted grid)
#define FILT   33
#define PAD    16

typedef __attribute__((ext_vector_type(8))) __bf16 bf16x8;
typedef __attribute__((ext_vector_type(4))) float  f32x4;

#define GLB(p) ((const __attribute__((address_space(1))) unsigned int*)(p))
#define LDSP(p) ((__attribute__((address_space(3))) unsigned int*)(p))

__device__ __forceinline__ unsigned short f2bf(float f) {
    union { __hip_bfloat16 h; unsigned short u; } cv;
    cv.h = __float2bfloat16(f);
    return cv.u;
}

// ---------------------------------------------------------------------------
// Kernel 1: per-row demean + std-normalize, fp32 -> bf16 (r1-proven, ~BW floor)
// ---------------------------------------------------------------------------
__global__ __launch_bounds__(256)
void normalize_kernel(const float* __restrict__ x, __hip_bfloat16* __restrict__ xn)
{
    const int lane = threadIdx.x & 63;
    const int row  = blockIdx.x * 4 + (threadIdx.x >> 6);

    const float4* xr = reinterpret_cast<const float4*>(x + (size_t)row * N_IN);
    float4 v[4];
    float s = 0.f, s2 = 0.f;
#pragma unroll
    for (int i = 0; i < 4; i++) {
        v[i] = xr[i * 64 + lane];
        s  += v[i].x + v[i].y + v[i].z + v[i].w;
        s2 += v[i].x * v[i].x + v[i].y * v[i].y + v[i].z * v[i].z + v[i].w * v[i].w;
    }
#pragma unroll
    for (int off = 32; off > 0; off >>= 1) {
        s  += __shfl_xor(s,  off, 64);
        s2 += __shfl_xor(s2, off, 64);
    }
    const float mu  = s * (1.0f / N_IN);
    const float var = fmaxf(s2 * (1.0f / N_IN) - mu * mu, 0.0f);
    const float inv = 1.0f / (sqrtf(var) + 1e-7f);

    ushort4* outv = reinterpret_cast<ushort4*>(xn + (size_t)row * N_IN);
#pragma unroll
    for (int i = 0; i < 4; i++) {
        ushort4 o;
        o.x = f2bf((v[i].x - mu) * inv);
        o.y = f2bf((v[i].y - mu) * inv);
        o.z = f2bf((v[i].z - mu) * inv);
        o.w = f2bf((v[i].w - mu) * inv);
        outv[i * 64 + lane] = o;
    }
}

// ---------------------------------------------------------------------------
// Kernel 2: Gaussian resolution filter + circular conv along n, fp32 -> bf16
// ---------------------------------------------------------------------------
__global__ __launch_bounds__(256)
void conv_kernel(const float* __restrict__ lm_raw, __hip_bfloat16* __restrict__ lm)
{
    __shared__ float row[N_IN];
    __shared__ float fw[FILT];
    const int tid = threadIdx.x;
    const int p   = blockIdx.x;

    if (tid < FILT) {
        float t = (tid - PAD) * (2.0f / FILT);
        float u = t * 10.0f;            // t / sigma0 (sigma0 = 0.1)
        fw[tid] = expf(-0.5f * u * u);
    }
    reinterpret_cast<float4*>(row)[tid] =
        reinterpret_cast<const float4*>(lm_raw + (size_t)p * N_IN)[tid];
    __syncthreads();

    float fsum = 0.f;
#pragma unroll
    for (int f = 0; f < FILT; f++) fsum += fw[f];
    const float inv = 1.0f / fsum;

    const int n0 = tid * 4;
    float o[4] = {0.f, 0.f, 0.f, 0.f};
#pragma unroll
    for (int f = 0; f < FILT; f++) {
        const float w = fw[f];
#pragma unroll
        for (int j = 0; j < 4; j++)
            o[j] += w * row[(n0 + j + f - PAD) & (N_IN - 1)];
    }
    ushort4 ov;
    ov.x = f2bf(o[0] * inv);
    ov.y = f2bf(o[1] * inv);
    ov.z = f2bf(o[2] * inv);
    ov.w = f2bf(o[3] * inv);
    reinterpret_cast<ushort4*>(lm + (size_t)p * N_IN)[tid] = ov;
}

// ---------------------------------------------------------------------------
// Kernel 3: GEMM  C[M,N] = A[M,K] * B[N,K]^T — 8-phase-template port (m201).
// 256x256 tile, BK=64, 512 thr (8 waves 2Mx4N), per-wave 128x64 (acc[8][4]).
// Double-buffered LDS 2 x (A[256][128B] + B[256][128B]) = 128 KiB.
// 4 phases per K-tile, each: {ds_read subtile || stage -> barrier ->
// lgkm(0)+sched_barrier -> setprio(1) 16 MFMA setprio(0) -> barrier}.
// All 8 gloads for kt+1 issue at phase 0 of kt; single vmcnt(0) per K-tile
// at phase-3 end (aged ~1900cy -> ~free, not an issue-adjacent drain).
// Swizzle for 128B rows: slot(16B) ^= (row&7) -> 8 lanes/slot = optimal
// 8 acc/bank; linear gload dest + pre-swizzled source + swizzled ds_read.
// T1 bijective XCD swizzle (nwg=256). B-frags reused across m-halves.
// ---------------------------------------------------------------------------
__global__ __launch_bounds__(512, 2)
void gemm_8ph(const __hip_bfloat16* __restrict__ A,
              const __hip_bfloat16* __restrict__ B,
              float* __restrict__ C,
              int M, int N, int K)
{
    __shared__ char smem[2][65536];   // per buf: A @0 (32K), B @32768 (32K)

    const int tid = threadIdx.x;
    const int l   = tid & 63;
    const int w   = tid >> 6;    // 0..7
    const int wm  = w >> 2;      // 0..1  (M direction, 128 rows)
    const int wn  = w & 3;       // 0..3  (N direction, 64 cols)

    // T1: bijective XCD swizzle (nwg=256 divisible by 8)
    const int o    = blockIdx.x;
    const int lin  = (o & 7) * (gridDim.x >> 3) + (o >> 3);
    const int tn   = lin & 3;          // N/256 = 4
    const int tm   = lin >> 2;         // M/256 = 64
    const size_t bm = (size_t)tm * 256;
    const size_t bn = (size_t)tn * 256;

    // ---- staging geometry: per gload 512thr x 16B = 64 rows x 128B ----
    // LDS linear: row = tid>>3, slot = tid&7; swizzle: source col slot^(row&7)
    const int srow = tid >> 3;                       // 0..63 (+64 per gload)
    const int scol = 16 * ((tid & 7) ^ (srow & 7));  // pre-swizzled byte col
    const char* gA = (const char*)(A + (bm + srow) * (size_t)K) + scol;
    const char* gB = (const char*)(B + (bn + srow) * (size_t)K) + scol;
    const size_t rowstep = (size_t)64 * K * 2;       // +64 rows (bytes)

    // 8 gloads = full K-tile (A 256 rows + B 256 rows)
#define STAGE8(kt, b) do {                                                            \
    const char* a_ = gA + (size_t)(kt) * 128;                                         \
    const char* b_ = gB + (size_t)(kt) * 128;                                         \
    char* La_ = &smem[(b)][0]     + tid * 16;                                         \
    char* Lb_ = &smem[(b)][32768] + tid * 16;                                         \
    __builtin_amdgcn_global_load_lds(GLB(a_),               LDSP(La_),         16, 0, 0); \
    __builtin_amdgcn_global_load_lds(GLB(a_ + rowstep),     LDSP(La_ + 8192),  16, 0, 0); \
    __builtin_amdgcn_global_load_lds(GLB(a_ + 2 * rowstep), LDSP(La_ + 16384), 16, 0, 0); \
    __builtin_amdgcn_global_load_lds(GLB(a_ + 3 * rowstep), LDSP(La_ + 24576), 16, 0, 0); \
    __builtin_amdgcn_global_load_lds(GLB(b_),               LDSP(Lb_),         16, 0, 0); \
    __builtin_amdgcn_global_load_lds(GLB(b_ + rowstep),     LDSP(Lb_ + 8192),  16, 0, 0); \
    __builtin_amdgcn_global_load_lds(GLB(b_ + 2 * rowstep), LDSP(Lb_ + 16384), 16, 0, 0); \
    __builtin_amdgcn_global_load_lds(GLB(b_ + 3 * rowstep), LDSP(Lb_ + 24576), 16, 0, 0); \
} while (0)

#define BAR() do { asm volatile("" ::: "memory");                  \
                   __builtin_amdgcn_s_barrier();                   \
                   asm volatile("" ::: "memory"); } while (0)
#define WAIT_LDS() do { asm volatile("s_waitcnt lgkmcnt(0)" ::: "memory"); \
                        __builtin_amdgcn_sched_barrier(0); } while (0)

    // ---- fragment-read geometry (swizzled ds_read, same involution) ----
    const int lr   = l & 15;
    const int kb   = l >> 4;                         // 16B sub-slot of K-step
    const int akey = lr & 7;
    const int slot0 = 16 * ((kb)     ^ akey);        // ks=0 slots 0..3
    const int slot1 = 16 * ((4 + kb) ^ akey);        // ks=1 slots 4..7
    const int abase = (wm * 128 + lr) * 128;         // + (mh*64 + m*16)*128
    const int bbase = 32768 + (wn * 64 + lr) * 128;  // + n*16*128

    f32x4 acc[8][4] = {};
    const int NT = K / 64;                           // 16 K-tiles

    STAGE8(0, 0);
    asm volatile("s_waitcnt vmcnt(0)" ::: "memory");
    BAR();

    for (int kt = 0; kt < NT; ++kt) {
        const int cur = kt & 1;
        const char* S = &smem[cur][0];
        bf16x8 bfr0[4], bfr1[4], afr[4];

        // ---- phase 0: (mh=0, ks=0) + full stage of kt+1 ----
#pragma unroll
        for (int n = 0; n < 4; n++) bfr0[n] = *(const bf16x8*)(S + bbase + n * 2048 + slot0);
#pragma unroll
        for (int m = 0; m < 4; m++) afr[m]  = *(const bf16x8*)(S + abase + m * 2048 + slot0);
        if (kt + 1 < NT) STAGE8(kt + 1, cur ^ 1);
        BAR(); WAIT_LDS();
        __builtin_amdgcn_s_setprio(1);
#pragma unroll
        for (int m = 0; m < 4; m++)
#pragma unroll
            for (int n = 0; n < 4; n++)
                acc[m][n] = __builtin_amdgcn_mfma_f32_16x16x32_bf16(afr[m], bfr0[n], acc[m][n], 0, 0, 0);
        __builtin_amdgcn_s_setprio(0);
        BAR();

        // ---- phase 1: (mh=1, ks=0), reuse bfr0 ----
#pragma unroll
        for (int m = 0; m < 4; m++) afr[m] = *(const bf16x8*)(S + abase + 8192 + m * 2048 + slot0);
        BAR(); WAIT_LDS();
        __builtin_amdgcn_s_setprio(1);
#pragma unroll
        for (int m = 0; m < 4; m++)
#pragma unroll
            for (int n = 0; n < 4; n++)
                acc[m + 4][n] = __builtin_amdgcn_mfma_f32_16x16x32_bf16(afr[m], bfr0[n], acc[m + 4][n], 0, 0, 0);
        __builtin_amdgcn_s_setprio(0);
        BAR();

        // ---- phase 2: (mh=0, ks=1) ----
#pragma unroll
        for (int n = 0; n < 4; n++) bfr1[n] = *(const bf16x8*)(S + bbase + n * 2048 + slot1);
#pragma unroll
        for (int m = 0; m < 4; m++) afr[m]  = *(const bf16x8*)(S + abase + m * 2048 + slot1);
        BAR(); WAIT_LDS();
        __builtin_amdgcn_s_setprio(1);
#pragma unroll
        for (int m = 0; m < 4; m++)
#pragma unroll
            for (int n = 0; n < 4; n++)
                acc[m][n] = __builtin_amdgcn_mfma_f32_16x16x32_bf16(afr[m], bfr1[n], acc[m][n], 0, 0, 0);
        __builtin_amdgcn_s_setprio(0);
        BAR();

        // ---- phase 3: (mh=1, ks=1), reuse bfr1 ----
#pragma unroll
        for (int m = 0; m < 4; m++) afr[m] = *(const bf16x8*)(S + abase + 8192 + m * 2048 + slot1);
        BAR(); WAIT_LDS();
        __builtin_amdgcn_s_setprio(1);
#pragma unroll
        for (int m = 0; m < 4; m++)
#pragma unroll
            for (int n = 0; n < 4; n++)
                acc[m + 4][n] = __builtin_amdgcn_mfma_f32_16x16x32_bf16(afr[m], bfr1[n], acc[m + 4][n], 0, 0, 0);
        __builtin_amdgcn_s_setprio(0);
        // end of K-tile: kt+1's loads (issued ph0, ~1900cy ago) must be in LDS
        asm volatile("s_waitcnt vmcnt(0)" ::: "memory");
        BAR();
    }
#undef STAGE8
#undef BAR
#undef WAIT_LDS

    // epilogue: C/D layout col = lane&15, row = (lane>>4)*4 + reg  [m89/m91]
    const int crow = (l >> 4) * 4;
    const int ccol = l & 15;
#pragma unroll
    for (int m = 0; m < 8; m++)
#pragma unroll
        for (int n = 0; n < 4; n++) {
#pragma unroll
            for (int r = 0; r < 4; r++) {
                const size_t row = bm + wm * 128 + m * 16 + crow + r;
                const size_t col = bn + wn * 64 + n * 16 + ccol;
                C[row * N + col] = acc[m][n][r];
            }
        }
}

// ---------------------------------------------------------------------------
extern "C" void kernel_launch(void* const* d_in, const int* in_sizes, int n_in,
                              void* d_out, int out_size, void* d_ws, size_t ws_size,
                              hipStream_t stream) {
    const float* x      = (const float*)d_in[0];   // [M, 1024] fp32
    const float* lm_raw = (const float*)d_in[1];   // [32, 32, 1024] fp32
    float* out = (float*)d_out;                    // [M, 32, 32] fp32

    const int M = in_sizes[0] / N_IN;              // 16384

    // workspace layout: xn bf16 [M,1024] (32 MiB) | lm bf16 [1024,1024] (2 MiB)
    __hip_bfloat16* xn = (__hip_bfloat16*)d_ws;
    __hip_bfloat16* lm = (__hip_bfloat16*)((char*)d_ws + (size_t)M * N_IN * 2);

    normalize_kernel<<<M / 4, 256, 0, stream>>>(x, xn);
    conv_kernel<<<N_P, 256, 0, stream>>>(lm_raw, lm);

    const int nblk = (M / 256) * (N_P / 256);      // 64 * 4 = 256
    gemm_8ph<<<nblk, dim3(512), 0, stream>>>(xn, lm, out, M, N_P, N_IN);
}